// Round 4
// baseline (604.481 us; speedup 1.0000x reference)
//
#include <hip/hip_runtime.h>
#include <hip/hip_bf16.h>
#include <hip/hip_fp16.h>

#define NFEAT  128
#define HC     64
#define HEADS  4
#define NHID   16
#define NCLASS 40
#define NEG    0.2f
#define BN_EPS 1e-5f

__device__ __forceinline__ float leaky(float a) { return (a > 0.f) ? a : NEG * a; }

// ---------------------------------------------------------------------------
// Kernel 1: h1 = x @ W1 (W1 in LDS), one wave per row, lane = channel.
// h1 stored as fp16. Per-head attention scores in fp32.
// ---------------------------------------------------------------------------
__global__ __launch_bounds__(256) void k_gemm1(
    const float* __restrict__ x, const float* __restrict__ W1,
    const float* __restrict__ att_s, const float* __restrict__ att_d,
    __half* __restrict__ h1, float* __restrict__ as1, float* __restrict__ ad1,
    int n)
{
    __shared__ float sW[NFEAT * HC];     // 32 KB
    __shared__ float sx[4][NFEAT];
    for (int i = threadIdx.x; i < NFEAT * HC; i += 256) sW[i] = W1[i];
    __syncthreads();

    const int wave = threadIdx.x >> 6, lane = threadIdx.x & 63;
    const float av = att_s[lane];
    const float bv = att_d[lane];
    const int stride = gridDim.x * 4;

    for (int row = blockIdx.x * 4 + wave; row < n; row += stride) {
        sx[wave][lane]      = x[(size_t)row * NFEAT + lane];
        sx[wave][lane + 64] = x[(size_t)row * NFEAT + lane + 64];
        __threadfence_block();

        float acc = 0.f;
        #pragma unroll
        for (int k4 = 0; k4 < NFEAT; k4 += 4) {
            const float4 xv = *(const float4*)&sx[wave][k4];
            acc = fmaf(xv.x, sW[(k4 + 0) * HC + lane], acc);
            acc = fmaf(xv.y, sW[(k4 + 1) * HC + lane], acc);
            acc = fmaf(xv.z, sW[(k4 + 2) * HC + lane], acc);
            acc = fmaf(xv.w, sW[(k4 + 3) * HC + lane], acc);
        }

        h1[(size_t)row * HC + lane] = __float2half_rn(acc);

        float s = acc * av, d = acc * bv;
        #pragma unroll
        for (int off = 8; off >= 1; off >>= 1) {
            s += __shfl_xor(s, off, 64);
            d += __shfl_xor(d, off, 64);
        }
        if ((lane & 15) == 0) {
            as1[row * HEADS + (lane >> 4)] = s;
            ad1[row * HEADS + (lane >> 4)] = d;
        }
        __threadfence_block();
    }
}

// ---------------------------------------------------------------------------
// CSR build: degree count -> 3-kernel scan -> fill (rowptr doubles as cursor)
// ---------------------------------------------------------------------------
__global__ __launch_bounds__(256) void k_count(
    const int* __restrict__ edst, int* __restrict__ deg, int E)
{
    int i = blockIdx.x * 256 + threadIdx.x;
    if (i < E) atomicAdd(deg + edst[i], 1);
}

__global__ __launch_bounds__(1024) void k_scan1(
    const int* __restrict__ deg, int* __restrict__ rowptr,
    int* __restrict__ bsum, int n)
{
    __shared__ int wsum[16];
    const int tid = threadIdx.x, lane = tid & 63, w = tid >> 6;
    const int idx = blockIdx.x * 1024 + tid;
    int v = (idx < n) ? deg[idx] : 0;
    int sc = v;
    #pragma unroll
    for (int off = 1; off < 64; off <<= 1) {
        int t = __shfl_up(sc, off, 64);
        if (lane >= off) sc += t;
    }
    if (lane == 63) wsum[w] = sc;
    __syncthreads();
    if (w == 0 && lane < 16) {
        int s = wsum[lane];
        #pragma unroll
        for (int off = 1; off < 16; off <<= 1) {
            int t = __shfl_up(s, off, 16);
            if (lane >= off) s += t;
        }
        wsum[lane] = s;
    }
    __syncthreads();
    const int woff = (w > 0) ? wsum[w - 1] : 0;
    if (idx < n) rowptr[idx + 1] = woff + sc;
    if (tid == 0) bsum[blockIdx.x] = wsum[15];
}

__global__ __launch_bounds__(128) void k_scan2(int* __restrict__ bsum, int nb)
{
    __shared__ int ws2[2];
    const int tid = threadIdx.x, lane = tid & 63, w = tid >> 6;
    int v = (tid < nb) ? bsum[tid] : 0;
    int sc = v;
    #pragma unroll
    for (int off = 1; off < 64; off <<= 1) {
        int t = __shfl_up(sc, off, 64);
        if (lane >= off) sc += t;
    }
    if (lane == 63) ws2[w] = sc;
    __syncthreads();
    const int incl = sc + ((w == 1) ? ws2[0] : 0);
    if (tid < nb) bsum[tid] = incl - v;     // exclusive
}

// rowptr[i] (i in [0,n)) = START of node i after this; rowptr[0]=0
__global__ __launch_bounds__(256) void k_scan3(
    int* __restrict__ rowptr, const int* __restrict__ bsum, int n)
{
    const int idx = blockIdx.x * 256 + threadIdx.x;
    if (idx < n - 1) rowptr[idx + 1] += bsum[idx >> 10];
    if (idx == 0) rowptr[0] = 0;
}

// atomicAdd on rowptr[d] itself: post-fill rowptr[d] = END of node d
__global__ __launch_bounds__(256) void k_fill(
    const int* __restrict__ esrc, const int* __restrict__ edst,
    int* __restrict__ rowptr, int* __restrict__ csr, int E)
{
    int i = blockIdx.x * 256 + threadIdx.x;
    if (i >= E) return;
    const int d = edst[i];
    const int pos = atomicAdd(rowptr + d, 1);
    csr[pos] = esrc[i];
}

// ---------------------------------------------------------------------------
// Kernel agg1: one wave per node; half-wave = one edge (half2 loads, 2 ch/lane).
// Prefetch exp-scores into LDS; denominator via butterfly.
// Fused: normalize + bias1 + BN + ReLU + GEMM2 + layer-2 scores. g in fp16.
// ---------------------------------------------------------------------------
__global__ __launch_bounds__(256) void k_agg1(
    const int* __restrict__ csr, const int* __restrict__ rowptr,
    const __half* __restrict__ h1, const float* __restrict__ as1,
    const float* __restrict__ ad1,
    const float* __restrict__ bias1, const float* __restrict__ gamma,
    const float* __restrict__ beta, const float* __restrict__ mean,
    const float* __restrict__ var,
    const float* __restrict__ W2, const float* __restrict__ ats2,
    const float* __restrict__ atd2,
    __half* __restrict__ g, float* __restrict__ as2o, float* __restrict__ ad2o,
    int n)
{
    __shared__ float sW[HC * NCLASS];    // 10 KB
    __shared__ float sh[4][HC];
    __shared__ float sE[4][64 * 4];      // exp per edge per head
    __shared__ int   sS[4][64];
    for (int i = threadIdx.x; i < HC * NCLASS; i += 256) sW[i] = W2[i];
    __syncthreads();

    const int wave = threadIdx.x >> 6, lane = threadIdx.x & 63;
    const int c = lane & 31, half_id = lane >> 5;
    const int hh = c >> 3;               // head of channel pair (2c,2c+1)

    // epilogue constants for lanes 0..31 (channel pair 2c,2c+1)
    float2 b1v = {0.f, 0.f}, scv = {0.f, 0.f}, shv = {0.f, 0.f};
    if (lane < 32) {
        b1v = *(const float2*)(bias1 + 2 * c);
        const float2 gmv = *(const float2*)(gamma + 2 * c);
        const float2 vrv = *(const float2*)(var   + 2 * c);
        const float2 mnv = *(const float2*)(mean  + 2 * c);
        const float2 btv = *(const float2*)(beta  + 2 * c);
        scv.x = gmv.x * rsqrtf(vrv.x + BN_EPS);
        scv.y = gmv.y * rsqrtf(vrv.y + BN_EPS);
        shv.x = btv.x - mnv.x * scv.x;
        shv.y = btv.y - mnv.y * scv.y;
    }
    const float a2 = (lane < NCLASS) ? ats2[lane] : 0.f;
    const float d2 = (lane < NCLASS) ? atd2[lane] : 0.f;

    for (int node = blockIdx.x * 4 + wave; node < n; node += gridDim.x * 4) {
        const float4 adv = *(const float4*)(ad1 + node * HEADS);
        const float4 sv4 = *(const float4*)(as1 + node * HEADS);
        float4 eself;
        eself.x = __expf(leaky(sv4.x + adv.x));
        eself.y = __expf(leaky(sv4.y + adv.y));
        eself.z = __expf(leaky(sv4.z + adv.z));
        eself.w = __expf(leaky(sv4.w + adv.w));

        float2 acc0 = {0.f, 0.f}, acc1 = {0.f, 0.f};
        float4 dpart = {0.f, 0.f, 0.f, 0.f};

        const int start = (node == 0) ? 0 : rowptr[node - 1];
        const int end   = rowptr[node];

        for (int base = start; base < end; base += 64) {
            const int m = min(64, end - base);
            float4 e4 = {0.f, 0.f, 0.f, 0.f};
            int eid = 0;
            if (lane < m) {
                eid = csr[base + lane];
                const float4 s4 = *(const float4*)(as1 + (size_t)eid * HEADS);
                e4.x = __expf(leaky(s4.x + adv.x));
                e4.y = __expf(leaky(s4.y + adv.y));
                e4.z = __expf(leaky(s4.z + adv.z));
                e4.w = __expf(leaky(s4.w + adv.w));
            }
            dpart.x += e4.x; dpart.y += e4.y; dpart.z += e4.z; dpart.w += e4.w;
            *(float4*)&sE[wave][lane * 4] = e4;
            sS[wave][lane] = eid;
            __threadfence_block();

            const float* eB = &sE[wave][0];
            const int*   sB = &sS[wave][0];
            int i = 0;
            for (; i + 4 <= m; i += 4) {           // 4 edges: 2 per half-wave
                const int j0 = i + half_id, j1 = i + 2 + half_id;
                const int s0 = sB[j0], s1 = sB[j1];
                const float e0 = eB[j0 * 4 + hh], e1 = eB[j1 * 4 + hh];
                const float2 f0 = __half22float2(*(const __half2*)(h1 + (size_t)s0 * HC + 2 * c));
                const float2 f1 = __half22float2(*(const __half2*)(h1 + (size_t)s1 * HC + 2 * c));
                acc0.x = fmaf(e0, f0.x, acc0.x); acc0.y = fmaf(e0, f0.y, acc0.y);
                acc1.x = fmaf(e1, f1.x, acc1.x); acc1.y = fmaf(e1, f1.y, acc1.y);
            }
            for (; i < m; i += 2) {
                const int j = i + half_id;
                if (j < m) {
                    const int s = sB[j];
                    const float e = eB[j * 4 + hh];
                    const float2 f = __half22float2(*(const __half2*)(h1 + (size_t)s * HC + 2 * c));
                    acc0.x = fmaf(e, f.x, acc0.x); acc0.y = fmaf(e, f.y, acc0.y);
                }
            }
            __threadfence_block();
        }

        // combine the two half-wave edge accumulators
        float2 acc = {acc0.x + acc1.x, acc0.y + acc1.y};
        acc.x += __shfl_xor(acc.x, 32, 64);
        acc.y += __shfl_xor(acc.y, 32, 64);

        #pragma unroll
        for (int off = 32; off >= 1; off >>= 1) {
            dpart.x += __shfl_xor(dpart.x, off, 64);
            dpart.y += __shfl_xor(dpart.y, off, 64);
            dpart.z += __shfl_xor(dpart.z, off, 64);
            dpart.w += __shfl_xor(dpart.w, off, 64);
        }

        if (lane < 32) {
            const float es = (hh == 0) ? eself.x : (hh == 1) ? eself.y
                           : (hh == 2) ? eself.z : eself.w;
            const float dp = (hh == 0) ? dpart.x : (hh == 1) ? dpart.y
                           : (hh == 2) ? dpart.z : dpart.w;
            const float den = es + dp;
            const float2 fs = __half22float2(*(const __half2*)(h1 + (size_t)node * HC + 2 * c));
            float vx = (acc.x + es * fs.x) / den + b1v.x;
            float vy = (acc.y + es * fs.y) / den + b1v.y;
            vx = fmaxf(fmaf(vx, scv.x, shv.x), 0.f);
            vy = fmaxf(fmaf(vy, scv.y, shv.y), 0.f);
            float2 v2 = {vx, vy};
            *(float2*)&sh[wave][2 * c] = v2;
        }
        __threadfence_block();

        float gv = 0.f;
        if (lane < NCLASS) {
            #pragma unroll
            for (int k = 0; k < HC; ++k)
                gv = fmaf(sh[wave][k], sW[k * NCLASS + lane], gv);
            g[(size_t)node * NCLASS + lane] = __float2half_rn(gv);
        }
        float sv = gv * a2, dv = gv * d2;
        #pragma unroll
        for (int off = 32; off >= 1; off >>= 1) {
            sv += __shfl_xor(sv, off, 64);
            dv += __shfl_xor(dv, off, 64);
        }
        if (lane == 0) { as2o[node] = sv; ad2o[node] = dv; }
        __threadfence_block();
    }
}

// ---------------------------------------------------------------------------
// Kernel agg2: one wave per node; 20-lane group = one edge (half2, 2 ch/lane),
// 3 edges per wave-iter. Final bias fused.
// ---------------------------------------------------------------------------
__global__ __launch_bounds__(256) void k_agg2(
    const int* __restrict__ csr, const int* __restrict__ rowptr,
    const __half* __restrict__ g, const float* __restrict__ as2,
    const float* __restrict__ ad2, const float* __restrict__ bias2,
    float* __restrict__ out, int n)
{
    __shared__ float sE[4][64];
    __shared__ int   sS[4][64];
    const int wave = threadIdx.x >> 6, lane = threadIdx.x & 63;
    const int grp = lane / 20;           // 0,1,2 active; 3 idle in gather
    const int c   = lane - grp * 20;     // channel pair (2c,2c+1)

    float2 b2v = {0.f, 0.f};
    if (lane < 20) b2v = *(const float2*)(bias2 + 2 * c);

    for (int node = blockIdx.x * 4 + wave; node < n; node += gridDim.x * 4) {
        const float ad2d = ad2[node];
        const float eself = __expf(leaky(as2[node] + ad2d));
        float2 acc0 = {0.f, 0.f}, acc1 = {0.f, 0.f};
        float dpart = 0.f;

        const int start = (node == 0) ? 0 : rowptr[node - 1];
        const int end   = rowptr[node];

        for (int base = start; base < end; base += 64) {
            const int m = min(64, end - base);
            float e = 0.f;
            int eid = 0;
            if (lane < m) {
                eid = csr[base + lane];
                e = __expf(leaky(as2[eid] + ad2d));
            }
            dpart += e;
            sE[wave][lane] = e;
            sS[wave][lane] = eid;
            __threadfence_block();

            const float* eB = &sE[wave][0];
            const int*   sB = &sS[wave][0];
            int i = 0;
            for (; i + 6 <= m; i += 6) {         // 6 edges: 2 per group
                if (grp < 3) {
                    const int j0 = i + grp, j1 = i + 3 + grp;
                    const int s0 = sB[j0], s1 = sB[j1];
                    const float e0 = eB[j0], e1 = eB[j1];
                    const float2 f0 = __half22float2(*(const __half2*)(g + (size_t)s0 * NCLASS + 2 * c));
                    const float2 f1 = __half22float2(*(const __half2*)(g + (size_t)s1 * NCLASS + 2 * c));
                    acc0.x = fmaf(e0, f0.x, acc0.x); acc0.y = fmaf(e0, f0.y, acc0.y);
                    acc1.x = fmaf(e1, f1.x, acc1.x); acc1.y = fmaf(e1, f1.y, acc1.y);
                }
            }
            for (; i < m; i += 3) {
                const int j = i + grp;
                if (grp < 3 && j < m) {
                    const int s = sB[j];
                    const float e0 = eB[j];
                    const float2 f = __half22float2(*(const __half2*)(g + (size_t)s * NCLASS + 2 * c));
                    acc0.x = fmaf(e0, f.x, acc0.x); acc0.y = fmaf(e0, f.y, acc0.y);
                }
            }
            __threadfence_block();
        }

        float ax = acc0.x + acc1.x, ay = acc0.y + acc1.y;
        const int i1 = (lane + 20) & 63, i2 = (lane + 40) & 63;
        const float bx = __shfl(ax, i1, 64), by = __shfl(ay, i1, 64);
        const float cx = __shfl(ax, i2, 64), cy = __shfl(ay, i2, 64);
        ax += bx + cx; ay += by + cy;

        #pragma unroll
        for (int off = 32; off >= 1; off >>= 1)
            dpart += __shfl_xor(dpart, off, 64);
        const float den = dpart + eself;

        if (lane < 20) {
            const float2 fs = __half22float2(*(const __half2*)(g + (size_t)node * NCLASS + 2 * c));
            float2 r;
            r.x = (ax + eself * fs.x) / den + b2v.x;
            r.y = (ay + eself * fs.y) / den + b2v.y;
            *(float2*)(out + (size_t)node * NCLASS + 2 * c) = r;
        }
    }
}

extern "C" void kernel_launch(void* const* d_in, const int* in_sizes, int n_in,
                              void* d_out, int out_size, void* d_ws, size_t ws_size,
                              hipStream_t stream)
{
    const float* x    = (const float*)d_in[0];
    const int*   ei   = (const int*)  d_in[1];
    const float* W1   = (const float*)d_in[2];
    const float* as1w = (const float*)d_in[3];
    const float* ad1w = (const float*)d_in[4];
    const float* b1   = (const float*)d_in[5];
    const float* gm   = (const float*)d_in[6];
    const float* bt   = (const float*)d_in[7];
    const float* mn   = (const float*)d_in[8];
    const float* vr   = (const float*)d_in[9];
    const float* W2   = (const float*)d_in[10];
    const float* as2w = (const float*)d_in[11];
    const float* ad2w = (const float*)d_in[12];
    const float* b2   = (const float*)d_in[13];

    const int n = in_sizes[0] / NFEAT;           // 100000
    const int E = in_sizes[1] / 2;               // 1600000
    const int* esrc = ei;
    const int* edst = ei + E;

    // workspace (float units):
    // h1h(32n) | as1(4n) | ad1(4n) | g(20n) | as2(n) | ad2(n) |
    // deg(n) | rowptr(n+1) | bsum(98) | csr(E)
    float*  ws   = (float*)d_ws;
    __half* h1   = (__half*)ws;
    float*  a_s1 = ws   + (size_t)n * 32;
    float*  a_d1 = a_s1 + (size_t)n * 4;
    __half* gbuf = (__half*)(a_d1 + (size_t)n * 4);
    float*  a_s2 = a_d1 + (size_t)n * 4 + (size_t)n * 20;
    float*  a_d2 = a_s2 + n;
    int*    deg    = (int*)(a_d2 + n);
    int*    rowptr = deg + n;
    const int nb1 = (n + 1023) / 1024;
    int*    bsum   = rowptr + (n + 1);
    int*    csr    = bsum + nb1;
    float*  outv = (float*)d_out;

    hipMemsetAsync(deg, 0, (size_t)n * sizeof(int), stream);

    const int eb = (E + 255) / 256;
    const int nblk = (n + 3) / 4;

    k_count<<<eb, 256, 0, stream>>>(edst, deg, E);
    k_scan1<<<nb1, 1024, 0, stream>>>(deg, rowptr, bsum, n);
    k_scan2<<<1, 128, 0, stream>>>(bsum, nb1);
    k_scan3<<<(n + 255) / 256, 256, 0, stream>>>(rowptr, bsum, n);
    k_fill <<<eb, 256, 0, stream>>>(esrc, edst, rowptr, csr, E);
    k_gemm1<<<2048, 256, 0, stream>>>(x, W1, as1w, ad1w, h1, a_s1, a_d1, n);
    k_agg1 <<<nblk, 256, 0, stream>>>(csr, rowptr, h1, a_s1, a_d1, b1, gm, bt, mn, vr,
                                      W2, as2w, ad2w, gbuf, a_s2, a_d2, n);
    k_agg2 <<<nblk, 256, 0, stream>>>(csr, rowptr, gbuf, a_s2, a_d2, b2, outv, n);
}

// Round 5
// 501.282 us; speedup vs baseline: 1.2059x; 1.2059x over previous
//
#include <hip/hip_runtime.h>
#include <hip/hip_bf16.h>
#include <hip/hip_fp16.h>

#define NFEAT  128
#define HC     64
#define HEADS  4
#define NHID   16
#define NCLASS 40
#define NEG    0.2f
#define BN_EPS 1e-5f

__device__ __forceinline__ float leaky(float a) { return (a > 0.f) ? a : NEG * a; }

// ---------------------------------------------------------------------------
// Kernel 1: h1 = x @ W1 (W1 in LDS), one wave per row, lane = channel.
// h1 stored as fp16. Per-head attention scores in fp32.
// ---------------------------------------------------------------------------
__global__ __launch_bounds__(256) void k_gemm1(
    const float* __restrict__ x, const float* __restrict__ W1,
    const float* __restrict__ att_s, const float* __restrict__ att_d,
    __half* __restrict__ h1, float* __restrict__ as1, float* __restrict__ ad1,
    int n)
{
    __shared__ float sW[NFEAT * HC];     // 32 KB
    __shared__ float sx[4][NFEAT];
    for (int i = threadIdx.x; i < NFEAT * HC; i += 256) sW[i] = W1[i];
    __syncthreads();

    const int wave = threadIdx.x >> 6, lane = threadIdx.x & 63;
    const float av = att_s[lane];
    const float bv = att_d[lane];
    const int stride = gridDim.x * 4;

    for (int row = blockIdx.x * 4 + wave; row < n; row += stride) {
        sx[wave][lane]      = x[(size_t)row * NFEAT + lane];
        sx[wave][lane + 64] = x[(size_t)row * NFEAT + lane + 64];
        __threadfence_block();

        float acc = 0.f;
        #pragma unroll
        for (int k4 = 0; k4 < NFEAT; k4 += 4) {
            const float4 xv = *(const float4*)&sx[wave][k4];
            acc = fmaf(xv.x, sW[(k4 + 0) * HC + lane], acc);
            acc = fmaf(xv.y, sW[(k4 + 1) * HC + lane], acc);
            acc = fmaf(xv.z, sW[(k4 + 2) * HC + lane], acc);
            acc = fmaf(xv.w, sW[(k4 + 3) * HC + lane], acc);
        }

        h1[(size_t)row * HC + lane] = __float2half_rn(acc);

        float s = acc * av, d = acc * bv;
        #pragma unroll
        for (int off = 8; off >= 1; off >>= 1) {
            s += __shfl_xor(s, off, 64);
            d += __shfl_xor(d, off, 64);
        }
        if ((lane & 15) == 0) {
            as1[row * HEADS + (lane >> 4)] = s;
            ad1[row * HEADS + (lane >> 4)] = d;
        }
        __threadfence_block();
    }
}

// ---------------------------------------------------------------------------
// CSR build: degree count -> 3-kernel scan -> fill (rowptr doubles as cursor)
// ---------------------------------------------------------------------------
__global__ __launch_bounds__(256) void k_count(
    const int* __restrict__ edst, int* __restrict__ deg, int E)
{
    int i = blockIdx.x * 256 + threadIdx.x;
    if (i < E) atomicAdd(deg + edst[i], 1);
}

__global__ __launch_bounds__(1024) void k_scan1(
    const int* __restrict__ deg, int* __restrict__ rowptr,
    int* __restrict__ bsum, int n)
{
    __shared__ int wsum[16];
    const int tid = threadIdx.x, lane = tid & 63, w = tid >> 6;
    const int idx = blockIdx.x * 1024 + tid;
    int v = (idx < n) ? deg[idx] : 0;
    int sc = v;
    #pragma unroll
    for (int off = 1; off < 64; off <<= 1) {
        int t = __shfl_up(sc, off, 64);
        if (lane >= off) sc += t;
    }
    if (lane == 63) wsum[w] = sc;
    __syncthreads();
    if (w == 0 && lane < 16) {
        int s = wsum[lane];
        #pragma unroll
        for (int off = 1; off < 16; off <<= 1) {
            int t = __shfl_up(s, off, 16);
            if (lane >= off) s += t;
        }
        wsum[lane] = s;
    }
    __syncthreads();
    const int woff = (w > 0) ? wsum[w - 1] : 0;
    if (idx < n) rowptr[idx + 1] = woff + sc;
    if (tid == 0) bsum[blockIdx.x] = wsum[15];
}

__global__ __launch_bounds__(128) void k_scan2(int* __restrict__ bsum, int nb)
{
    __shared__ int ws2[2];
    const int tid = threadIdx.x, lane = tid & 63, w = tid >> 6;
    int v = (tid < nb) ? bsum[tid] : 0;
    int sc = v;
    #pragma unroll
    for (int off = 1; off < 64; off <<= 1) {
        int t = __shfl_up(sc, off, 64);
        if (lane >= off) sc += t;
    }
    if (lane == 63) ws2[w] = sc;
    __syncthreads();
    const int incl = sc + ((w == 1) ? ws2[0] : 0);
    if (tid < nb) bsum[tid] = incl - v;     // exclusive
}

__global__ __launch_bounds__(256) void k_scan3(
    int* __restrict__ rowptr, const int* __restrict__ bsum, int n)
{
    const int idx = blockIdx.x * 256 + threadIdx.x;
    if (idx < n - 1) rowptr[idx + 1] += bsum[idx >> 10];
    if (idx == 0) rowptr[0] = 0;
}

// atomicAdd on rowptr[d] itself: post-fill rowptr[d] = END of node d
__global__ __launch_bounds__(256) void k_fill(
    const int* __restrict__ esrc, const int* __restrict__ edst,
    int* __restrict__ rowptr, int* __restrict__ csr, int E)
{
    int i = blockIdx.x * 256 + threadIdx.x;
    if (i >= E) return;
    const int d = edst[i];
    const int pos = atomicAdd(rowptr + d, 1);
    csr[pos] = esrc[i];
}

// ---------------------------------------------------------------------------
// Kernel agg1: one 16-lane group per node (4 nodes/wave, 16/block).
// Lane q owns channels 4q..4q+3 (fp16 half4 loads). Prefetch up to 32 edges
// per batch (lane q covers edges q and q+16), denominator via 4-round
// group butterfly. Fused epilogue: /den + bias1 + BN + ReLU + GEMM2
// (g padded to 64 fp16 ch) + layer-2 scores.
// ---------------------------------------------------------------------------
__global__ __launch_bounds__(256) void k_agg1(
    const int* __restrict__ csr, const int* __restrict__ rowptr,
    const __half* __restrict__ h1, const float* __restrict__ as1,
    const float* __restrict__ ad1,
    const float* __restrict__ bias1, const float* __restrict__ gamma,
    const float* __restrict__ beta, const float* __restrict__ mean,
    const float* __restrict__ var,
    const float* __restrict__ W2, const float* __restrict__ ats2,
    const float* __restrict__ atd2,
    __half* __restrict__ g, float* __restrict__ as2o, float* __restrict__ ad2o,
    int n)
{
    __shared__ float sW[NCLASS * HC];    // W2[k][c], 10 KB
    __shared__ float sh[16][68];         // per-group post-BN vector (pad 4)
    __shared__ float sE[16][132];        // per-group exp scores: 32 edges x 4 heads
    __shared__ int   sS[16][33];         // per-group src ids
    for (int i = threadIdx.x; i < NCLASS * HC; i += 256) sW[i] = W2[i];
    __syncthreads();

    const int gi = threadIdx.x >> 4;     // group index in block (0..15)
    const int q  = threadIdx.x & 15;     // lane in group
    const int myh = q >> 2;              // head of channels 4q..4q+3

    // per-channel epilogue constants (channels 4q..4q+3)
    const float4 b1v = *(const float4*)(bias1 + 4 * q);
    const float4 gmv = *(const float4*)(gamma + 4 * q);
    const float4 vrv = *(const float4*)(var   + 4 * q);
    const float4 mnv = *(const float4*)(mean  + 4 * q);
    const float4 btv = *(const float4*)(beta  + 4 * q);
    float4 scv, shv;
    scv.x = gmv.x * rsqrtf(vrv.x + BN_EPS);
    scv.y = gmv.y * rsqrtf(vrv.y + BN_EPS);
    scv.z = gmv.z * rsqrtf(vrv.z + BN_EPS);
    scv.w = gmv.w * rsqrtf(vrv.w + BN_EPS);
    shv.x = btv.x - mnv.x * scv.x;
    shv.y = btv.y - mnv.y * scv.y;
    shv.z = btv.z - mnv.z * scv.z;
    shv.w = btv.w - mnv.w * scv.w;
    float4 at2 = {0.f, 0.f, 0.f, 0.f}, dt2 = {0.f, 0.f, 0.f, 0.f};
    if (q < 10) {
        at2 = *(const float4*)(ats2 + 4 * q);
        dt2 = *(const float4*)(atd2 + 4 * q);
    }

    for (int node0 = blockIdx.x * 16; node0 < n; node0 += gridDim.x * 16) {
        const int node = node0 + gi;
        if (node >= n) continue;

        const float4 adv = *(const float4*)(ad1 + node * HEADS);
        const float4 sv4 = *(const float4*)(as1 + node * HEADS);
        float4 eself;
        eself.x = __expf(leaky(sv4.x + adv.x));
        eself.y = __expf(leaky(sv4.y + adv.y));
        eself.z = __expf(leaky(sv4.z + adv.z));
        eself.w = __expf(leaky(sv4.w + adv.w));
        const float es = (myh == 0) ? eself.x : (myh == 1) ? eself.y
                       : (myh == 2) ? eself.z : eself.w;

        // self contribution
        float2 raws = *(const float2*)(h1 + (size_t)node * HC + 4 * q);
        const float2 s0 = __half22float2(*(__half2*)&raws.x);
        const float2 s1 = __half22float2(*(__half2*)&raws.y);
        float4 acc;
        acc.x = es * s0.x; acc.y = es * s0.y;
        acc.z = es * s1.x; acc.w = es * s1.y;
        float4 dpart = {0.f, 0.f, 0.f, 0.f};

        const int start = (node == 0) ? 0 : rowptr[node - 1];
        const int end   = rowptr[node];

        for (int base = start; base < end; base += 32) {
            const int m = min(32, end - base);
            // prefetch: lane q covers edges base+q and base+q+16
            float4 ea = {0.f, 0.f, 0.f, 0.f}, eb = {0.f, 0.f, 0.f, 0.f};
            int ia = 0, ib = 0;
            if (q < m) {
                ia = csr[base + q];
                const float4 s4 = *(const float4*)(as1 + (size_t)ia * HEADS);
                ea.x = __expf(leaky(s4.x + adv.x));
                ea.y = __expf(leaky(s4.y + adv.y));
                ea.z = __expf(leaky(s4.z + adv.z));
                ea.w = __expf(leaky(s4.w + adv.w));
            }
            if (q + 16 < m) {
                ib = csr[base + q + 16];
                const float4 s4 = *(const float4*)(as1 + (size_t)ib * HEADS);
                eb.x = __expf(leaky(s4.x + adv.x));
                eb.y = __expf(leaky(s4.y + adv.y));
                eb.z = __expf(leaky(s4.z + adv.z));
                eb.w = __expf(leaky(s4.w + adv.w));
            }
            dpart.x += ea.x + eb.x; dpart.y += ea.y + eb.y;
            dpart.z += ea.z + eb.z; dpart.w += ea.w + eb.w;
            *(float4*)&sE[gi][4 * q] = ea;
            *(float4*)&sE[gi][4 * (q + 16)] = eb;
            sS[gi][q] = ia; sS[gi][q + 16] = ib;
            __threadfence_block();

            int j = 0;
            for (; j + 2 <= m; j += 2) {
                const int sa = sS[gi][j], sb = sS[gi][j + 1];
                const float fa = sE[gi][4 * j + myh];
                const float fb = sE[gi][4 * (j + 1) + myh];
                const float2 ra = *(const float2*)(h1 + (size_t)sa * HC + 4 * q);
                const float2 rb = *(const float2*)(h1 + (size_t)sb * HC + 4 * q);
                const float2 a0 = __half22float2(*(const __half2*)&ra.x);
                const float2 a1 = __half22float2(*(const __half2*)&ra.y);
                const float2 b0 = __half22float2(*(const __half2*)&rb.x);
                const float2 b1 = __half22float2(*(const __half2*)&rb.y);
                acc.x = fmaf(fa, a0.x, acc.x); acc.y = fmaf(fa, a0.y, acc.y);
                acc.z = fmaf(fa, a1.x, acc.z); acc.w = fmaf(fa, a1.y, acc.w);
                acc.x = fmaf(fb, b0.x, acc.x); acc.y = fmaf(fb, b0.y, acc.y);
                acc.z = fmaf(fb, b1.x, acc.z); acc.w = fmaf(fb, b1.y, acc.w);
            }
            if (j < m) {
                const int sa = sS[gi][j];
                const float fa = sE[gi][4 * j + myh];
                const float2 ra = *(const float2*)(h1 + (size_t)sa * HC + 4 * q);
                const float2 a0 = __half22float2(*(const __half2*)&ra.x);
                const float2 a1 = __half22float2(*(const __half2*)&ra.y);
                acc.x = fmaf(fa, a0.x, acc.x); acc.y = fmaf(fa, a0.y, acc.y);
                acc.z = fmaf(fa, a1.x, acc.z); acc.w = fmaf(fa, a1.y, acc.w);
            }
            __threadfence_block();
        }

        // group-local denominator reduction (4 rounds stay within 16 lanes)
        #pragma unroll
        for (int off = 8; off >= 1; off >>= 1) {
            dpart.x += __shfl_xor(dpart.x, off, 64);
            dpart.y += __shfl_xor(dpart.y, off, 64);
            dpart.z += __shfl_xor(dpart.z, off, 64);
            dpart.w += __shfl_xor(dpart.w, off, 64);
        }
        const float den = es + ((myh == 0) ? dpart.x : (myh == 1) ? dpart.y
                               : (myh == 2) ? dpart.z : dpart.w);
        const float rden = 1.f / den;

        float4 v;
        v.x = fmaxf(fmaf(acc.x * rden + b1v.x, scv.x, shv.x), 0.f);
        v.y = fmaxf(fmaf(acc.y * rden + b1v.y, scv.y, shv.y), 0.f);
        v.z = fmaxf(fmaf(acc.z * rden + b1v.z, scv.z, shv.z), 0.f);
        v.w = fmaxf(fmaf(acc.w * rden + b1v.w, scv.w, shv.w), 0.f);
        *(float4*)&sh[gi][4 * q] = v;
        __threadfence_block();

        // GEMM2: lane q (q<10) computes out channels 4q..4q+3
        float4 gacc = {0.f, 0.f, 0.f, 0.f};
        if (q < 10) {
            #pragma unroll 8
            for (int k = 0; k < HC; ++k) {
                const float hk = sh[gi][k];
                const float4 wv = *(const float4*)&sW[k * NCLASS + 4 * q];
                gacc.x = fmaf(hk, wv.x, gacc.x);
                gacc.y = fmaf(hk, wv.y, gacc.y);
                gacc.z = fmaf(hk, wv.z, gacc.z);
                gacc.w = fmaf(hk, wv.w, gacc.w);
            }
        }
        // store g padded to 64 fp16 channels (zeros for q>=10)
        __half2 p0 = __float22half2_rn({gacc.x, gacc.y});
        __half2 p1 = __float22half2_rn({gacc.z, gacc.w});
        float2 packed; *(__half2*)&packed.x = p0; *(__half2*)&packed.y = p1;
        *(float2*)(g + (size_t)node * HC + 4 * q) = packed;

        // layer-2 scores
        float sv = gacc.x * at2.x + gacc.y * at2.y + gacc.z * at2.z + gacc.w * at2.w;
        float dv = gacc.x * dt2.x + gacc.y * dt2.y + gacc.z * dt2.z + gacc.w * dt2.w;
        #pragma unroll
        for (int off = 8; off >= 1; off >>= 1) {
            sv += __shfl_xor(sv, off, 64);
            dv += __shfl_xor(dv, off, 64);
        }
        if (q == 0) { as2o[node] = sv; ad2o[node] = dv; }
        __threadfence_block();
    }
}

// ---------------------------------------------------------------------------
// Kernel agg2: one 16-lane group per node; g rows padded to 64 fp16 ch.
// Lane q owns channels 4q..4q+3; q<10 writes final float4 output.
// ---------------------------------------------------------------------------
__global__ __launch_bounds__(256) void k_agg2(
    const int* __restrict__ csr, const int* __restrict__ rowptr,
    const __half* __restrict__ g, const float* __restrict__ as2,
    const float* __restrict__ ad2, const float* __restrict__ bias2,
    float* __restrict__ out, int n)
{
    __shared__ float sE[16][34];
    __shared__ int   sS[16][33];
    const int gi = threadIdx.x >> 4;
    const int q  = threadIdx.x & 15;

    float4 b2v = {0.f, 0.f, 0.f, 0.f};
    if (q < 10) b2v = *(const float4*)(bias2 + 4 * q);

    for (int node0 = blockIdx.x * 16; node0 < n; node0 += gridDim.x * 16) {
        const int node = node0 + gi;
        if (node >= n) continue;

        const float ad2d = ad2[node];
        const float eself = __expf(leaky(as2[node] + ad2d));

        float2 raws = *(const float2*)(g + (size_t)node * HC + 4 * q);
        const float2 s0 = __half22float2(*(__half2*)&raws.x);
        const float2 s1 = __half22float2(*(__half2*)&raws.y);
        float4 acc;
        acc.x = eself * s0.x; acc.y = eself * s0.y;
        acc.z = eself * s1.x; acc.w = eself * s1.y;
        float dpart = 0.f;

        const int start = (node == 0) ? 0 : rowptr[node - 1];
        const int end   = rowptr[node];

        for (int base = start; base < end; base += 32) {
            const int m = min(32, end - base);
            float ea = 0.f, eb = 0.f;
            int ia = 0, ib = 0;
            if (q < m) {
                ia = csr[base + q];
                ea = __expf(leaky(as2[ia] + ad2d));
            }
            if (q + 16 < m) {
                ib = csr[base + q + 16];
                eb = __expf(leaky(as2[ib] + ad2d));
            }
            dpart += ea + eb;
            sE[gi][q] = ea; sE[gi][q + 16] = eb;
            sS[gi][q] = ia; sS[gi][q + 16] = ib;
            __threadfence_block();

            int j = 0;
            for (; j + 2 <= m; j += 2) {
                const int sa = sS[gi][j], sb = sS[gi][j + 1];
                const float fa = sE[gi][j], fb = sE[gi][j + 1];
                const float2 ra = *(const float2*)(g + (size_t)sa * HC + 4 * q);
                const float2 rb = *(const float2*)(g + (size_t)sb * HC + 4 * q);
                const float2 a0 = __half22float2(*(const __half2*)&ra.x);
                const float2 a1 = __half22float2(*(const __half2*)&ra.y);
                const float2 b0 = __half22float2(*(const __half2*)&rb.x);
                const float2 b1 = __half22float2(*(const __half2*)&rb.y);
                acc.x = fmaf(fa, a0.x, acc.x); acc.y = fmaf(fa, a0.y, acc.y);
                acc.z = fmaf(fa, a1.x, acc.z); acc.w = fmaf(fa, a1.y, acc.w);
                acc.x = fmaf(fb, b0.x, acc.x); acc.y = fmaf(fb, b0.y, acc.y);
                acc.z = fmaf(fb, b1.x, acc.z); acc.w = fmaf(fb, b1.y, acc.w);
            }
            if (j < m) {
                const int sa = sS[gi][j];
                const float fa = sE[gi][j];
                const float2 ra = *(const float2*)(g + (size_t)sa * HC + 4 * q);
                const float2 a0 = __half22float2(*(const __half2*)&ra.x);
                const float2 a1 = __half22float2(*(const __half2*)&ra.y);
                acc.x = fmaf(fa, a0.x, acc.x); acc.y = fmaf(fa, a0.y, acc.y);
                acc.z = fmaf(fa, a1.x, acc.z); acc.w = fmaf(fa, a1.y, acc.w);
            }
            __threadfence_block();
        }

        #pragma unroll
        for (int off = 8; off >= 1; off >>= 1)
            dpart += __shfl_xor(dpart, off, 64);
        const float rden = 1.f / (dpart + eself);

        if (q < 10) {
            float4 r;
            r.x = acc.x * rden + b2v.x;
            r.y = acc.y * rden + b2v.y;
            r.z = acc.z * rden + b2v.z;
            r.w = acc.w * rden + b2v.w;
            *(float4*)(out + (size_t)node * NCLASS + 4 * q) = r;
        }
    }
}

extern "C" void kernel_launch(void* const* d_in, const int* in_sizes, int n_in,
                              void* d_out, int out_size, void* d_ws, size_t ws_size,
                              hipStream_t stream)
{
    const float* x    = (const float*)d_in[0];
    const int*   ei   = (const int*)  d_in[1];
    const float* W1   = (const float*)d_in[2];
    const float* as1w = (const float*)d_in[3];
    const float* ad1w = (const float*)d_in[4];
    const float* b1   = (const float*)d_in[5];
    const float* gm   = (const float*)d_in[6];
    const float* bt   = (const float*)d_in[7];
    const float* mn   = (const float*)d_in[8];
    const float* vr   = (const float*)d_in[9];
    const float* W2   = (const float*)d_in[10];
    const float* as2w = (const float*)d_in[11];
    const float* ad2w = (const float*)d_in[12];
    const float* b2   = (const float*)d_in[13];

    const int n = in_sizes[0] / NFEAT;           // 100000
    const int E = in_sizes[1] / 2;               // 1600000
    const int* esrc = ei;
    const int* edst = ei + E;

    // workspace (float units):
    // h1h(32n) | as1(4n) | ad1(4n) | g64(32n fp16 = 32n floats? -> 64ch fp16 = 32 floats/node)
    // | as2(n) | ad2(n) | deg(n) | rowptr(n+1) | bsum | csr(E)
    float*  ws   = (float*)d_ws;
    __half* h1   = (__half*)ws;
    float*  a_s1 = ws   + (size_t)n * 32;
    float*  a_d1 = a_s1 + (size_t)n * 4;
    __half* gbuf = (__half*)(a_d1 + (size_t)n * 4);   // 64 fp16 ch = 32 floats/node
    float*  a_s2 = a_d1 + (size_t)n * 4 + (size_t)n * 32;
    float*  a_d2 = a_s2 + n;
    int*    deg    = (int*)(a_d2 + n);
    int*    rowptr = deg + n;
    const int nb1 = (n + 1023) / 1024;
    int*    bsum   = rowptr + (n + 1);
    int*    csr    = bsum + nb1;
    float*  outv = (float*)d_out;

    hipMemsetAsync(deg, 0, (size_t)n * sizeof(int), stream);

    const int eb = (E + 255) / 256;
    const int nblk = (n + 15) / 16;

    k_count<<<eb, 256, 0, stream>>>(edst, deg, E);
    k_scan1<<<nb1, 1024, 0, stream>>>(deg, rowptr, bsum, n);
    k_scan2<<<1, 128, 0, stream>>>(bsum, nb1);
    k_scan3<<<(n + 255) / 256, 256, 0, stream>>>(rowptr, bsum, n);
    k_fill <<<eb, 256, 0, stream>>>(esrc, edst, rowptr, csr, E);
    k_gemm1<<<2048, 256, 0, stream>>>(x, W1, as1w, ad1w, h1, a_s1, a_d1, n);
    k_agg1 <<<nblk, 256, 0, stream>>>(csr, rowptr, h1, a_s1, a_d1, b1, gm, bt, mn, vr,
                                      W2, as2w, ad2w, gbuf, a_s2, a_d2, n);
    k_agg2 <<<nblk, 256, 0, stream>>>(csr, rowptr, gbuf, a_s2, a_d2, b2, outv, n);
}

// Round 6
// 360.933 us; speedup vs baseline: 1.6748x; 1.3889x over previous
//
#include <hip/hip_runtime.h>
#include <hip/hip_bf16.h>
#include <hip/hip_fp16.h>

#define NFEAT  128
#define HC     64
#define HEADS  4
#define NHID   16
#define NCLASS 40
#define NEG    0.2f
#define BN_EPS 1e-5f

#define BK_SH   9          // 512 nodes per bucket
#define CHUNK   8192       // edges per histogram/scatter workgroup
#define STAGE   12288      // LDS staging capacity in k_build (bucket avg ~8200)

__device__ __forceinline__ float leaky(float a) { return (a > 0.f) ? a : NEG * a; }

// ---------------------------------------------------------------------------
// Kernel 1: h1 = x @ W1 (W1 in LDS), one wave per row, lane = channel.
// h1 stored as fp16. Per-head attention scores in fp32.
// ---------------------------------------------------------------------------
__global__ __launch_bounds__(256) void k_gemm1(
    const float* __restrict__ x, const float* __restrict__ W1,
    const float* __restrict__ att_s, const float* __restrict__ att_d,
    __half* __restrict__ h1, float* __restrict__ as1, float* __restrict__ ad1,
    int n)
{
    __shared__ float sW[NFEAT * HC];     // 32 KB
    __shared__ float sx[4][NFEAT];
    for (int i = threadIdx.x; i < NFEAT * HC; i += 256) sW[i] = W1[i];
    __syncthreads();

    const int wave = threadIdx.x >> 6, lane = threadIdx.x & 63;
    const float av = att_s[lane];
    const float bv = att_d[lane];
    const int stride = gridDim.x * 4;

    for (int row = blockIdx.x * 4 + wave; row < n; row += stride) {
        sx[wave][lane]      = x[(size_t)row * NFEAT + lane];
        sx[wave][lane + 64] = x[(size_t)row * NFEAT + lane + 64];
        __threadfence_block();

        float acc = 0.f;
        #pragma unroll
        for (int k4 = 0; k4 < NFEAT; k4 += 4) {
            const float4 xv = *(const float4*)&sx[wave][k4];
            acc = fmaf(xv.x, sW[(k4 + 0) * HC + lane], acc);
            acc = fmaf(xv.y, sW[(k4 + 1) * HC + lane], acc);
            acc = fmaf(xv.z, sW[(k4 + 2) * HC + lane], acc);
            acc = fmaf(xv.w, sW[(k4 + 3) * HC + lane], acc);
        }

        h1[(size_t)row * HC + lane] = __float2half_rn(acc);

        float s = acc * av, d = acc * bv;
        #pragma unroll
        for (int off = 8; off >= 1; off >>= 1) {
            s += __shfl_xor(s, off, 64);
            d += __shfl_xor(d, off, 64);
        }
        if ((lane & 15) == 0) {
            as1[row * HEADS + (lane >> 4)] = s;
            ad1[row * HEADS + (lane >> 4)] = d;
        }
        __threadfence_block();
    }
}

// ---------------------------------------------------------------------------
// CSR build, locality-preserving (no global atomics, no memset):
//  k_hist: per-chunk LDS histogram over dst buckets
//  k_colscan: per-bucket exclusive scan over chunks (in-place) + colsum
//  k_bscan: exclusive scan of colsum -> bstart
//  k_scatter: (src,dst) pairs into contiguous per-(chunk,bucket) runs
//  k_build: per-bucket LDS counting sort -> rowptr (inclusive end) + csr
// ---------------------------------------------------------------------------
__global__ __launch_bounds__(256) void k_hist(
    const int* __restrict__ edst, int* __restrict__ hist, int E, int nbk)
{
    __shared__ int lh[256];
    const int w = blockIdx.x, t = threadIdx.x;
    for (int i = t; i < nbk; i += 256) lh[i] = 0;
    __syncthreads();
    const int lo = w * CHUNK, hi = min(E, lo + CHUNK);
    for (int e = lo + t; e < hi; e += 256)
        atomicAdd(&lh[edst[e] >> BK_SH], 1);
    __syncthreads();
    for (int i = t; i < nbk; i += 256) hist[(size_t)w * nbk + i] = lh[i];
}

// one block per bucket; exclusive scan over chunk index (nw <= 256)
__global__ __launch_bounds__(256) void k_colscan(
    int* __restrict__ hist, int* __restrict__ colsum, int nbk, int nw)
{
    __shared__ int wred[4];
    const int b = blockIdx.x, t = threadIdx.x;
    const int lane = t & 63, w = t >> 6;
    const int v = (t < nw) ? hist[(size_t)t * nbk + b] : 0;
    int sc = v;
    #pragma unroll
    for (int off = 1; off < 64; off <<= 1) {
        int u = __shfl_up(sc, off, 64);
        if (lane >= off) sc += u;
    }
    if (lane == 63) wred[w] = sc;
    __syncthreads();
    if (t == 0) { int a = 0; for (int i = 0; i < 4; ++i) { int x = wred[i]; wred[i] = a; a += x; } }
    __syncthreads();
    const int excl = sc - v + wred[w];
    if (t < nw) hist[(size_t)t * nbk + b] = excl;
    if (t == nw - 1) colsum[b] = excl + v;
}

// single block: exclusive scan of colsum[0..nbk) -> bstart; bstart[nbk]=E
__global__ __launch_bounds__(256) void k_bscan(
    const int* __restrict__ colsum, int* __restrict__ bstart, int nbk, int E)
{
    __shared__ int wred[4];
    const int t = threadIdx.x, lane = t & 63, w = t >> 6;
    const int v = (t < nbk) ? colsum[t] : 0;
    int sc = v;
    #pragma unroll
    for (int off = 1; off < 64; off <<= 1) {
        int u = __shfl_up(sc, off, 64);
        if (lane >= off) sc += u;
    }
    if (lane == 63) wred[w] = sc;
    __syncthreads();
    if (t == 0) { int a = 0; for (int i = 0; i < 4; ++i) { int x = wred[i]; wred[i] = a; a += x; } }
    __syncthreads();
    if (t < nbk) bstart[t] = sc - v + wred[w];
    if (t == 0) bstart[nbk] = E;
}

__global__ __launch_bounds__(256) void k_scatter(
    const int* __restrict__ esrc, const int* __restrict__ edst,
    const int* __restrict__ hist, const int* __restrict__ bstart,
    int2* __restrict__ pairs, int E, int nbk)
{
    __shared__ int cur[256];
    const int w = blockIdx.x, t = threadIdx.x;
    for (int i = t; i < nbk; i += 256)
        cur[i] = bstart[i] + hist[(size_t)w * nbk + i];
    __syncthreads();
    const int lo = w * CHUNK, hi = min(E, lo + CHUNK);
    for (int e = lo + t; e < hi; e += 256) {
        const int s = esrc[e], d = edst[e];
        const int pos = atomicAdd(&cur[d >> BK_SH], 1);
        pairs[pos] = make_int2(s, d);
    }
}

__global__ __launch_bounds__(256) void k_build(
    const int2* __restrict__ pairs, const int* __restrict__ bstart,
    int* __restrict__ rowptr, int* __restrict__ csr, int n, int nbk)
{
    __shared__ int cnt[512];
    __shared__ int cur[512];
    __shared__ int stage[STAGE];
    __shared__ int wred[4];
    const int b = blockIdx.x, t = threadIdx.x;
    const int base = bstart[b], eend = bstart[b + 1], m = eend - base;
    const int n0 = b << BK_SH;
    const int nn = min(512, n - n0);

    cnt[t] = 0; cnt[t + 256] = 0;
    __syncthreads();
    for (int e = base + t; e < eend; e += 256)
        atomicAdd(&cnt[pairs[e].y - n0], 1);
    __syncthreads();

    // block exclusive scan over 512 counts; thread t owns (2t, 2t+1)
    const int c0 = cnt[2 * t], c1 = cnt[2 * t + 1];
    const int s = c0 + c1;
    const int lane = t & 63, w = t >> 6;
    int sc = s;
    #pragma unroll
    for (int off = 1; off < 64; off <<= 1) {
        int u = __shfl_up(sc, off, 64);
        if (lane >= off) sc += u;
    }
    if (lane == 63) wred[w] = sc;
    __syncthreads();
    if (t == 0) { int a = 0; for (int i = 0; i < 4; ++i) { int x = wred[i]; wred[i] = a; a += x; } }
    __syncthreads();
    const int excl = sc - s + wred[w];
    cur[2 * t]     = excl;
    cur[2 * t + 1] = excl + c0;
    if (2 * t < nn)     rowptr[n0 + 2 * t]     = base + excl + c0;
    if (2 * t + 1 < nn) rowptr[n0 + 2 * t + 1] = base + excl + c0 + c1;
    __syncthreads();

    for (int e = base + t; e < eend; e += 256) {
        const int2 p = pairs[e];
        const int loc = atomicAdd(&cur[p.y - n0], 1);
        if (loc < STAGE) stage[loc] = p.x;
        else             csr[base + loc] = p.x;   // overflow safety
    }
    __syncthreads();
    const int lim = min(m, STAGE);
    for (int i = t; i < lim; i += 256) csr[base + i] = stage[i];
}

// ---------------------------------------------------------------------------
// Kernel agg1: one 16-lane group per node (4 nodes/wave, 16/block).
// Lane q owns channels 4q..4q+3 (fp16 half4 loads). Prefetch up to 32 edges
// per batch, denominator via 4-round group butterfly. Fused epilogue:
// /den + bias1 + BN + ReLU + GEMM2 (g padded to 64 fp16 ch) + layer-2 scores.
// ---------------------------------------------------------------------------
__global__ __launch_bounds__(256) void k_agg1(
    const int* __restrict__ csr, const int* __restrict__ rowptr,
    const __half* __restrict__ h1, const float* __restrict__ as1,
    const float* __restrict__ ad1,
    const float* __restrict__ bias1, const float* __restrict__ gamma,
    const float* __restrict__ beta, const float* __restrict__ mean,
    const float* __restrict__ var,
    const float* __restrict__ W2, const float* __restrict__ ats2,
    const float* __restrict__ atd2,
    __half* __restrict__ g, float* __restrict__ as2o, float* __restrict__ ad2o,
    int n)
{
    __shared__ float sW[NCLASS * HC];    // W2[k][c], 10 KB
    __shared__ float sh[16][68];
    __shared__ float sE[16][132];
    __shared__ int   sS[16][33];
    for (int i = threadIdx.x; i < NCLASS * HC; i += 256) sW[i] = W2[i];
    __syncthreads();

    const int gi = threadIdx.x >> 4;
    const int q  = threadIdx.x & 15;
    const int myh = q >> 2;

    const float4 b1v = *(const float4*)(bias1 + 4 * q);
    const float4 gmv = *(const float4*)(gamma + 4 * q);
    const float4 vrv = *(const float4*)(var   + 4 * q);
    const float4 mnv = *(const float4*)(mean  + 4 * q);
    const float4 btv = *(const float4*)(beta  + 4 * q);
    float4 scv, shv;
    scv.x = gmv.x * rsqrtf(vrv.x + BN_EPS);
    scv.y = gmv.y * rsqrtf(vrv.y + BN_EPS);
    scv.z = gmv.z * rsqrtf(vrv.z + BN_EPS);
    scv.w = gmv.w * rsqrtf(vrv.w + BN_EPS);
    shv.x = btv.x - mnv.x * scv.x;
    shv.y = btv.y - mnv.y * scv.y;
    shv.z = btv.z - mnv.z * scv.z;
    shv.w = btv.w - mnv.w * scv.w;
    float4 at2 = {0.f, 0.f, 0.f, 0.f}, dt2 = {0.f, 0.f, 0.f, 0.f};
    if (q < 10) {
        at2 = *(const float4*)(ats2 + 4 * q);
        dt2 = *(const float4*)(atd2 + 4 * q);
    }

    for (int node0 = blockIdx.x * 16; node0 < n; node0 += gridDim.x * 16) {
        const int node = node0 + gi;
        if (node >= n) continue;

        const float4 adv = *(const float4*)(ad1 + node * HEADS);
        const float4 sv4 = *(const float4*)(as1 + node * HEADS);
        float4 eself;
        eself.x = __expf(leaky(sv4.x + adv.x));
        eself.y = __expf(leaky(sv4.y + adv.y));
        eself.z = __expf(leaky(sv4.z + adv.z));
        eself.w = __expf(leaky(sv4.w + adv.w));
        const float es = (myh == 0) ? eself.x : (myh == 1) ? eself.y
                       : (myh == 2) ? eself.z : eself.w;

        float2 raws = *(const float2*)(h1 + (size_t)node * HC + 4 * q);
        const float2 s0 = __half22float2(*(__half2*)&raws.x);
        const float2 s1 = __half22float2(*(__half2*)&raws.y);
        float4 acc;
        acc.x = es * s0.x; acc.y = es * s0.y;
        acc.z = es * s1.x; acc.w = es * s1.y;
        float4 dpart = {0.f, 0.f, 0.f, 0.f};

        const int start = (node == 0) ? 0 : rowptr[node - 1];
        const int end   = rowptr[node];

        for (int base = start; base < end; base += 32) {
            const int m = min(32, end - base);
            float4 ea = {0.f, 0.f, 0.f, 0.f}, eb = {0.f, 0.f, 0.f, 0.f};
            int ia = 0, ib = 0;
            if (q < m) {
                ia = csr[base + q];
                const float4 s4 = *(const float4*)(as1 + (size_t)ia * HEADS);
                ea.x = __expf(leaky(s4.x + adv.x));
                ea.y = __expf(leaky(s4.y + adv.y));
                ea.z = __expf(leaky(s4.z + adv.z));
                ea.w = __expf(leaky(s4.w + adv.w));
            }
            if (q + 16 < m) {
                ib = csr[base + q + 16];
                const float4 s4 = *(const float4*)(as1 + (size_t)ib * HEADS);
                eb.x = __expf(leaky(s4.x + adv.x));
                eb.y = __expf(leaky(s4.y + adv.y));
                eb.z = __expf(leaky(s4.z + adv.z));
                eb.w = __expf(leaky(s4.w + adv.w));
            }
            dpart.x += ea.x + eb.x; dpart.y += ea.y + eb.y;
            dpart.z += ea.z + eb.z; dpart.w += ea.w + eb.w;
            *(float4*)&sE[gi][4 * q] = ea;
            *(float4*)&sE[gi][4 * (q + 16)] = eb;
            sS[gi][q] = ia; sS[gi][q + 16] = ib;
            __threadfence_block();

            int j = 0;
            for (; j + 2 <= m; j += 2) {
                const int sa = sS[gi][j], sb = sS[gi][j + 1];
                const float fa = sE[gi][4 * j + myh];
                const float fb = sE[gi][4 * (j + 1) + myh];
                const float2 ra = *(const float2*)(h1 + (size_t)sa * HC + 4 * q);
                const float2 rb = *(const float2*)(h1 + (size_t)sb * HC + 4 * q);
                const float2 a0 = __half22float2(*(const __half2*)&ra.x);
                const float2 a1 = __half22float2(*(const __half2*)&ra.y);
                const float2 b0 = __half22float2(*(const __half2*)&rb.x);
                const float2 b1 = __half22float2(*(const __half2*)&rb.y);
                acc.x = fmaf(fa, a0.x, acc.x); acc.y = fmaf(fa, a0.y, acc.y);
                acc.z = fmaf(fa, a1.x, acc.z); acc.w = fmaf(fa, a1.y, acc.w);
                acc.x = fmaf(fb, b0.x, acc.x); acc.y = fmaf(fb, b0.y, acc.y);
                acc.z = fmaf(fb, b1.x, acc.z); acc.w = fmaf(fb, b1.y, acc.w);
            }
            if (j < m) {
                const int sa = sS[gi][j];
                const float fa = sE[gi][4 * j + myh];
                const float2 ra = *(const float2*)(h1 + (size_t)sa * HC + 4 * q);
                const float2 a0 = __half22float2(*(const __half2*)&ra.x);
                const float2 a1 = __half22float2(*(const __half2*)&ra.y);
                acc.x = fmaf(fa, a0.x, acc.x); acc.y = fmaf(fa, a0.y, acc.y);
                acc.z = fmaf(fa, a1.x, acc.z); acc.w = fmaf(fa, a1.y, acc.w);
            }
            __threadfence_block();
        }

        #pragma unroll
        for (int off = 8; off >= 1; off >>= 1) {
            dpart.x += __shfl_xor(dpart.x, off, 64);
            dpart.y += __shfl_xor(dpart.y, off, 64);
            dpart.z += __shfl_xor(dpart.z, off, 64);
            dpart.w += __shfl_xor(dpart.w, off, 64);
        }
        const float den = es + ((myh == 0) ? dpart.x : (myh == 1) ? dpart.y
                               : (myh == 2) ? dpart.z : dpart.w);
        const float rden = 1.f / den;

        float4 v;
        v.x = fmaxf(fmaf(acc.x * rden + b1v.x, scv.x, shv.x), 0.f);
        v.y = fmaxf(fmaf(acc.y * rden + b1v.y, scv.y, shv.y), 0.f);
        v.z = fmaxf(fmaf(acc.z * rden + b1v.z, scv.z, shv.z), 0.f);
        v.w = fmaxf(fmaf(acc.w * rden + b1v.w, scv.w, shv.w), 0.f);
        *(float4*)&sh[gi][4 * q] = v;
        __threadfence_block();

        float4 gacc = {0.f, 0.f, 0.f, 0.f};
        if (q < 10) {
            #pragma unroll 8
            for (int k = 0; k < HC; ++k) {
                const float hk = sh[gi][k];
                const float4 wv = *(const float4*)&sW[k * NCLASS + 4 * q];
                gacc.x = fmaf(hk, wv.x, gacc.x);
                gacc.y = fmaf(hk, wv.y, gacc.y);
                gacc.z = fmaf(hk, wv.z, gacc.z);
                gacc.w = fmaf(hk, wv.w, gacc.w);
            }
        }
        __half2 p0 = __float22half2_rn({gacc.x, gacc.y});
        __half2 p1 = __float22half2_rn({gacc.z, gacc.w});
        float2 packed; *(__half2*)&packed.x = p0; *(__half2*)&packed.y = p1;
        *(float2*)(g + (size_t)node * HC + 4 * q) = packed;

        float sv = gacc.x * at2.x + gacc.y * at2.y + gacc.z * at2.z + gacc.w * at2.w;
        float dv = gacc.x * dt2.x + gacc.y * dt2.y + gacc.z * dt2.z + gacc.w * dt2.w;
        #pragma unroll
        for (int off = 8; off >= 1; off >>= 1) {
            sv += __shfl_xor(sv, off, 64);
            dv += __shfl_xor(dv, off, 64);
        }
        if (q == 0) { as2o[node] = sv; ad2o[node] = dv; }
        __threadfence_block();
    }
}

// ---------------------------------------------------------------------------
// Kernel agg2: one 16-lane group per node; g rows padded to 64 fp16 ch.
// ---------------------------------------------------------------------------
__global__ __launch_bounds__(256) void k_agg2(
    const int* __restrict__ csr, const int* __restrict__ rowptr,
    const __half* __restrict__ g, const float* __restrict__ as2,
    const float* __restrict__ ad2, const float* __restrict__ bias2,
    float* __restrict__ out, int n)
{
    __shared__ float sE[16][34];
    __shared__ int   sS[16][33];
    const int gi = threadIdx.x >> 4;
    const int q  = threadIdx.x & 15;

    float4 b2v = {0.f, 0.f, 0.f, 0.f};
    if (q < 10) b2v = *(const float4*)(bias2 + 4 * q);

    for (int node0 = blockIdx.x * 16; node0 < n; node0 += gridDim.x * 16) {
        const int node = node0 + gi;
        if (node >= n) continue;

        const float ad2d = ad2[node];
        const float eself = __expf(leaky(as2[node] + ad2d));

        float2 raws = *(const float2*)(g + (size_t)node * HC + 4 * q);
        const float2 s0 = __half22float2(*(__half2*)&raws.x);
        const float2 s1 = __half22float2(*(__half2*)&raws.y);
        float4 acc;
        acc.x = eself * s0.x; acc.y = eself * s0.y;
        acc.z = eself * s1.x; acc.w = eself * s1.y;
        float dpart = 0.f;

        const int start = (node == 0) ? 0 : rowptr[node - 1];
        const int end   = rowptr[node];

        for (int base = start; base < end; base += 32) {
            const int m = min(32, end - base);
            float ea = 0.f, eb = 0.f;
            int ia = 0, ib = 0;
            if (q < m) {
                ia = csr[base + q];
                ea = __expf(leaky(as2[ia] + ad2d));
            }
            if (q + 16 < m) {
                ib = csr[base + q + 16];
                eb = __expf(leaky(as2[ib] + ad2d));
            }
            dpart += ea + eb;
            sE[gi][q] = ea; sE[gi][q + 16] = eb;
            sS[gi][q] = ia; sS[gi][q + 16] = ib;
            __threadfence_block();

            int j = 0;
            for (; j + 2 <= m; j += 2) {
                const int sa = sS[gi][j], sb = sS[gi][j + 1];
                const float fa = sE[gi][j], fb = sE[gi][j + 1];
                const float2 ra = *(const float2*)(g + (size_t)sa * HC + 4 * q);
                const float2 rb = *(const float2*)(g + (size_t)sb * HC + 4 * q);
                const float2 a0 = __half22float2(*(const __half2*)&ra.x);
                const float2 a1 = __half22float2(*(const __half2*)&ra.y);
                const float2 b0 = __half22float2(*(const __half2*)&rb.x);
                const float2 b1 = __half22float2(*(const __half2*)&rb.y);
                acc.x = fmaf(fa, a0.x, acc.x); acc.y = fmaf(fa, a0.y, acc.y);
                acc.z = fmaf(fa, a1.x, acc.z); acc.w = fmaf(fa, a1.y, acc.w);
                acc.x = fmaf(fb, b0.x, acc.x); acc.y = fmaf(fb, b0.y, acc.y);
                acc.z = fmaf(fb, b1.x, acc.z); acc.w = fmaf(fb, b1.y, acc.w);
            }
            if (j < m) {
                const int sa = sS[gi][j];
                const float fa = sE[gi][j];
                const float2 ra = *(const float2*)(g + (size_t)sa * HC + 4 * q);
                const float2 a0 = __half22float2(*(const __half2*)&ra.x);
                const float2 a1 = __half22float2(*(const __half2*)&ra.y);
                acc.x = fmaf(fa, a0.x, acc.x); acc.y = fmaf(fa, a0.y, acc.y);
                acc.z = fmaf(fa, a1.x, acc.z); acc.w = fmaf(fa, a1.y, acc.w);
            }
            __threadfence_block();
        }

        #pragma unroll
        for (int off = 8; off >= 1; off >>= 1)
            dpart += __shfl_xor(dpart, off, 64);
        const float rden = 1.f / (dpart + eself);

        if (q < 10) {
            float4 r;
            r.x = acc.x * rden + b2v.x;
            r.y = acc.y * rden + b2v.y;
            r.z = acc.z * rden + b2v.z;
            r.w = acc.w * rden + b2v.w;
            *(float4*)(out + (size_t)node * NCLASS + 4 * q) = r;
        }
    }
}

extern "C" void kernel_launch(void* const* d_in, const int* in_sizes, int n_in,
                              void* d_out, int out_size, void* d_ws, size_t ws_size,
                              hipStream_t stream)
{
    const float* x    = (const float*)d_in[0];
    const int*   ei   = (const int*)  d_in[1];
    const float* W1   = (const float*)d_in[2];
    const float* as1w = (const float*)d_in[3];
    const float* ad1w = (const float*)d_in[4];
    const float* b1   = (const float*)d_in[5];
    const float* gm   = (const float*)d_in[6];
    const float* bt   = (const float*)d_in[7];
    const float* mn   = (const float*)d_in[8];
    const float* vr   = (const float*)d_in[9];
    const float* W2   = (const float*)d_in[10];
    const float* as2w = (const float*)d_in[11];
    const float* ad2w = (const float*)d_in[12];
    const float* b2   = (const float*)d_in[13];

    const int n = in_sizes[0] / NFEAT;           // 100000
    const int E = in_sizes[1] / 2;               // 1600000
    const int* esrc = ei;
    const int* edst = ei + E;

    const int nbk = (n + 511) >> BK_SH;          // 196 buckets
    const int nw  = (E + CHUNK - 1) / CHUNK;     // 196 chunks

    // workspace (float units):
    // h1(32n) | as1(4n) | ad1(4n) | g(32n) | as2(n) | ad2(n)      [74n, even]
    // | pairs(2E ints) | csr(E) | rowptr(n) | hist(nw*nbk) | colsum(nbk) | bstart(nbk+1)
    float*  ws   = (float*)d_ws;
    __half* h1   = (__half*)ws;
    float*  a_s1 = ws   + (size_t)n * 32;
    float*  a_d1 = a_s1 + (size_t)n * 4;
    __half* gbuf = (__half*)(a_d1 + (size_t)n * 4);
    float*  a_s2 = a_d1 + (size_t)n * 4 + (size_t)n * 32;
    float*  a_d2 = a_s2 + n;
    int2*   pairs  = (int2*)(a_d2 + n);
    int*    csr    = (int*)(pairs + E);
    int*    rowptr = csr + E;
    int*    hist   = rowptr + n;
    int*    colsum = hist + (size_t)nw * nbk;
    int*    bstart = colsum + nbk;
    float*  outv = (float*)d_out;

    const int nblk = (n + 15) / 16;

    k_hist   <<<nw, 256, 0, stream>>>(edst, hist, E, nbk);
    k_colscan<<<nbk, 256, 0, stream>>>(hist, colsum, nbk, nw);
    k_bscan  <<<1, 256, 0, stream>>>(colsum, bstart, nbk, E);
    k_scatter<<<nw, 256, 0, stream>>>(esrc, edst, hist, bstart, pairs, E, nbk);
    k_build  <<<nbk, 256, 0, stream>>>(pairs, bstart, rowptr, csr, n, nbk);
    k_gemm1  <<<2048, 256, 0, stream>>>(x, W1, as1w, ad1w, h1, a_s1, a_d1, n);
    k_agg1   <<<nblk, 256, 0, stream>>>(csr, rowptr, h1, a_s1, a_d1, b1, gm, bt, mn, vr,
                                        W2, as2w, ad2w, gbuf, a_s2, a_d2, n);
    k_agg2   <<<nblk, 256, 0, stream>>>(csr, rowptr, gbuf, a_s2, a_d2, b2, outv, n);
}

// Round 7
// 295.423 us; speedup vs baseline: 2.0462x; 1.2218x over previous
//
#include <hip/hip_runtime.h>
#include <hip/hip_bf16.h>
#include <hip/hip_fp16.h>

#define NFEAT  128
#define HC     64
#define HEADS  4
#define NHID   16
#define NCLASS 40
#define NEG    0.2f
#define BN_EPS 1e-5f

#define BK_SH   9          // 512 nodes per bucket
#define CHUNK   8192       // edges per histogram/scatter workgroup
#define STAGE   12288      // LDS staging capacity in k_build (bucket avg ~8200)

typedef _Float16 half8_t __attribute__((ext_vector_type(8)));
typedef float    f32x4_t __attribute__((ext_vector_type(4)));

__device__ __forceinline__ float leaky(float a) { return (a > 0.f) ? a : NEG * a; }

// ---------------------------------------------------------------------------
// Kernel 1 (MFMA): h1 = x @ W1 via v_mfma_f32_16x16x32_f16.
// One wave per 16-row slab; W1 fragments held in registers (16 frags);
// scores a_s/a_d computed from fp32 accumulators via quad reductions.
// A layout: A[m=lane&15][k=quad*8+j]; B: B[k=quad*8+j][c=lane&15];
// D: row=quad*4+reg, col=lane&15  (learn_hip m89-verified mapping).
// ---------------------------------------------------------------------------
__global__ __launch_bounds__(256) void k_gemm1(
    const float* __restrict__ x, const float* __restrict__ W1,
    const float* __restrict__ att_s, const float* __restrict__ att_d,
    __half* __restrict__ h1, float* __restrict__ as1, float* __restrict__ ad1,
    int n)
{
    const int wave = threadIdx.x >> 6, lane = threadIdx.x & 63;
    const int quad = lane >> 4, l16 = lane & 15;

    // B fragments: bfrag[ks][ct][j] = W1[ks*32+quad*8+j][ct*16+l16]
    half8_t bfrag[4][4];
    #pragma unroll
    for (int ks = 0; ks < 4; ++ks)
        #pragma unroll
        for (int ct = 0; ct < 4; ++ct)
            #pragma unroll
            for (int j = 0; j < 8; ++j)
                bfrag[ks][ct][j] =
                    (_Float16)W1[(ks * 32 + quad * 8 + j) * HC + ct * 16 + l16];

    // attention weight for channel ct*16+l16 (head == ct)
    float avs[4], avd[4];
    #pragma unroll
    for (int ct = 0; ct < 4; ++ct) {
        avs[ct] = att_s[ct * 16 + l16];
        avd[ct] = att_d[ct * 16 + l16];
    }

    const int nslab = (n + 15) >> 4;
    for (int slab = blockIdx.x * 4 + wave; slab < nslab; slab += gridDim.x * 4) {
        const int rowbase = slab * 16;
        const int arow = min(rowbase + l16, n - 1);
        const float* xp = x + (size_t)arow * NFEAT;

        f32x4_t acc[4] = {{0.f,0.f,0.f,0.f},{0.f,0.f,0.f,0.f},
                          {0.f,0.f,0.f,0.f},{0.f,0.f,0.f,0.f}};
        #pragma unroll
        for (int ks = 0; ks < 4; ++ks) {
            const float4 xa = *(const float4*)(xp + ks * 32 + quad * 8);
            const float4 xb = *(const float4*)(xp + ks * 32 + quad * 8 + 4);
            half8_t af;
            af[0] = (_Float16)xa.x; af[1] = (_Float16)xa.y;
            af[2] = (_Float16)xa.z; af[3] = (_Float16)xa.w;
            af[4] = (_Float16)xb.x; af[5] = (_Float16)xb.y;
            af[6] = (_Float16)xb.z; af[7] = (_Float16)xb.w;
            #pragma unroll
            for (int ct = 0; ct < 4; ++ct)
                acc[ct] = __builtin_amdgcn_mfma_f32_16x16x32_f16(
                    af, bfrag[ks][ct], acc[ct], 0, 0, 0);
        }

        // epilogue: lane holds rows quad*4+reg, col ct*16+l16
        #pragma unroll
        for (int reg = 0; reg < 4; ++reg) {
            const int row = rowbase + quad * 4 + reg;
            const bool valid = row < n;

            float4 ps, pd;
            ps.x = acc[0][reg] * avs[0]; pd.x = acc[0][reg] * avd[0];
            ps.y = acc[1][reg] * avs[1]; pd.y = acc[1][reg] * avd[1];
            ps.z = acc[2][reg] * avs[2]; pd.z = acc[2][reg] * avd[2];
            ps.w = acc[3][reg] * avs[3]; pd.w = acc[3][reg] * avd[3];
            #pragma unroll
            for (int off = 8; off >= 1; off >>= 1) {
                ps.x += __shfl_xor(ps.x, off, 64); pd.x += __shfl_xor(pd.x, off, 64);
                ps.y += __shfl_xor(ps.y, off, 64); pd.y += __shfl_xor(pd.y, off, 64);
                ps.z += __shfl_xor(ps.z, off, 64); pd.z += __shfl_xor(pd.z, off, 64);
                ps.w += __shfl_xor(ps.w, off, 64); pd.w += __shfl_xor(pd.w, off, 64);
            }
            if (valid) {
                #pragma unroll
                for (int ct = 0; ct < 4; ++ct)
                    h1[(size_t)row * HC + ct * 16 + l16] =
                        __float2half_rn(acc[ct][reg]);
                if (l16 == 0) {
                    *(float4*)(as1 + (size_t)row * HEADS) = ps;
                    *(float4*)(ad1 + (size_t)row * HEADS) = pd;
                }
            }
        }
    }
}

// ---------------------------------------------------------------------------
// CSR build, locality-preserving (no global atomics, no memset):
//  k_hist: per-chunk LDS histogram over dst buckets
//  k_colscan: per-bucket exclusive scan over chunks (in-place) + colsum
//  k_bscan: exclusive scan of colsum -> bstart
//  k_scatter: (src,dst) pairs into contiguous per-(chunk,bucket) runs
//  k_build: per-bucket LDS counting sort -> rowptr (inclusive end) + csr
// ---------------------------------------------------------------------------
__global__ __launch_bounds__(256) void k_hist(
    const int* __restrict__ edst, int* __restrict__ hist, int E, int nbk)
{
    __shared__ int lh[256];
    const int w = blockIdx.x, t = threadIdx.x;
    for (int i = t; i < nbk; i += 256) lh[i] = 0;
    __syncthreads();
    const int lo = w * CHUNK, hi = min(E, lo + CHUNK);
    for (int e = lo + t; e < hi; e += 256)
        atomicAdd(&lh[edst[e] >> BK_SH], 1);
    __syncthreads();
    for (int i = t; i < nbk; i += 256) hist[(size_t)w * nbk + i] = lh[i];
}

__global__ __launch_bounds__(256) void k_colscan(
    int* __restrict__ hist, int* __restrict__ colsum, int nbk, int nw)
{
    __shared__ int wred[4];
    const int b = blockIdx.x, t = threadIdx.x;
    const int lane = t & 63, w = t >> 6;
    const int v = (t < nw) ? hist[(size_t)t * nbk + b] : 0;
    int sc = v;
    #pragma unroll
    for (int off = 1; off < 64; off <<= 1) {
        int u = __shfl_up(sc, off, 64);
        if (lane >= off) sc += u;
    }
    if (lane == 63) wred[w] = sc;
    __syncthreads();
    if (t == 0) { int a = 0; for (int i = 0; i < 4; ++i) { int xx = wred[i]; wred[i] = a; a += xx; } }
    __syncthreads();
    const int excl = sc - v + wred[w];
    if (t < nw) hist[(size_t)t * nbk + b] = excl;
    if (t == nw - 1) colsum[b] = excl + v;
}

__global__ __launch_bounds__(256) void k_bscan(
    const int* __restrict__ colsum, int* __restrict__ bstart, int nbk, int E)
{
    __shared__ int wred[4];
    const int t = threadIdx.x, lane = t & 63, w = t >> 6;
    const int v = (t < nbk) ? colsum[t] : 0;
    int sc = v;
    #pragma unroll
    for (int off = 1; off < 64; off <<= 1) {
        int u = __shfl_up(sc, off, 64);
        if (lane >= off) sc += u;
    }
    if (lane == 63) wred[w] = sc;
    __syncthreads();
    if (t == 0) { int a = 0; for (int i = 0; i < 4; ++i) { int xx = wred[i]; wred[i] = a; a += xx; } }
    __syncthreads();
    if (t < nbk) bstart[t] = sc - v + wred[w];
    if (t == 0) bstart[nbk] = E;
}

__global__ __launch_bounds__(256) void k_scatter(
    const int* __restrict__ esrc, const int* __restrict__ edst,
    const int* __restrict__ hist, const int* __restrict__ bstart,
    int2* __restrict__ pairs, int E, int nbk)
{
    __shared__ int cur[256];
    const int w = blockIdx.x, t = threadIdx.x;
    for (int i = t; i < nbk; i += 256)
        cur[i] = bstart[i] + hist[(size_t)w * nbk + i];
    __syncthreads();
    const int lo = w * CHUNK, hi = min(E, lo + CHUNK);
    for (int e = lo + t; e < hi; e += 256) {
        const int s = esrc[e], d = edst[e];
        const int pos = atomicAdd(&cur[d >> BK_SH], 1);
        pairs[pos] = make_int2(s, d);
    }
}

__global__ __launch_bounds__(256) void k_build(
    const int2* __restrict__ pairs, const int* __restrict__ bstart,
    int* __restrict__ rowptr, int* __restrict__ csr, int n, int nbk)
{
    __shared__ int cnt[512];
    __shared__ int cur[512];
    __shared__ int stage[STAGE];
    __shared__ int wred[4];
    const int b = blockIdx.x, t = threadIdx.x;
    const int base = bstart[b], eend = bstart[b + 1], m = eend - base;
    const int n0 = b << BK_SH;
    const int nn = min(512, n - n0);

    cnt[t] = 0; cnt[t + 256] = 0;
    __syncthreads();
    for (int e = base + t; e < eend; e += 256)
        atomicAdd(&cnt[pairs[e].y - n0], 1);
    __syncthreads();

    const int c0 = cnt[2 * t], c1 = cnt[2 * t + 1];
    const int s = c0 + c1;
    const int lane = t & 63, w = t >> 6;
    int sc = s;
    #pragma unroll
    for (int off = 1; off < 64; off <<= 1) {
        int u = __shfl_up(sc, off, 64);
        if (lane >= off) sc += u;
    }
    if (lane == 63) wred[w] = sc;
    __syncthreads();
    if (t == 0) { int a = 0; for (int i = 0; i < 4; ++i) { int xx = wred[i]; wred[i] = a; a += xx; } }
    __syncthreads();
    const int excl = sc - s + wred[w];
    cur[2 * t]     = excl;
    cur[2 * t + 1] = excl + c0;
    if (2 * t < nn)     rowptr[n0 + 2 * t]     = base + excl + c0;
    if (2 * t + 1 < nn) rowptr[n0 + 2 * t + 1] = base + excl + c0 + c1;
    __syncthreads();

    for (int e = base + t; e < eend; e += 256) {
        const int2 p = pairs[e];
        const int loc = atomicAdd(&cur[p.y - n0], 1);
        if (loc < STAGE) stage[loc] = p.x;
        else             csr[base + loc] = p.x;
    }
    __syncthreads();
    const int lim = min(m, STAGE);
    for (int i = t; i < lim; i += 256) csr[base + i] = stage[i];
}

// ---------------------------------------------------------------------------
// Kernel agg1: one 16-lane group per node (4 nodes/wave, 16/block).
// Lane q owns channels 4q..4q+3 (fp16 half4 loads). Prefetch up to 32 edges
// per batch, denominator via 4-round group butterfly. Fused epilogue:
// /den + bias1 + BN + ReLU + GEMM2 (g padded to 64 fp16 ch) + layer-2 scores.
// ---------------------------------------------------------------------------
__global__ __launch_bounds__(256) void k_agg1(
    const int* __restrict__ csr, const int* __restrict__ rowptr,
    const __half* __restrict__ h1, const float* __restrict__ as1,
    const float* __restrict__ ad1,
    const float* __restrict__ bias1, const float* __restrict__ gamma,
    const float* __restrict__ beta, const float* __restrict__ mean,
    const float* __restrict__ var,
    const float* __restrict__ W2, const float* __restrict__ ats2,
    const float* __restrict__ atd2,
    __half* __restrict__ g, float* __restrict__ as2o, float* __restrict__ ad2o,
    int n)
{
    __shared__ float sW[NCLASS * HC];
    __shared__ float sh[16][68];
    __shared__ float sE[16][132];
    __shared__ int   sS[16][33];
    for (int i = threadIdx.x; i < NCLASS * HC; i += 256) sW[i] = W2[i];
    __syncthreads();

    const int gi = threadIdx.x >> 4;
    const int q  = threadIdx.x & 15;
    const int myh = q >> 2;

    const float4 b1v = *(const float4*)(bias1 + 4 * q);
    const float4 gmv = *(const float4*)(gamma + 4 * q);
    const float4 vrv = *(const float4*)(var   + 4 * q);
    const float4 mnv = *(const float4*)(mean  + 4 * q);
    const float4 btv = *(const float4*)(beta  + 4 * q);
    float4 scv, shv;
    scv.x = gmv.x * rsqrtf(vrv.x + BN_EPS);
    scv.y = gmv.y * rsqrtf(vrv.y + BN_EPS);
    scv.z = gmv.z * rsqrtf(vrv.z + BN_EPS);
    scv.w = gmv.w * rsqrtf(vrv.w + BN_EPS);
    shv.x = btv.x - mnv.x * scv.x;
    shv.y = btv.y - mnv.y * scv.y;
    shv.z = btv.z - mnv.z * scv.z;
    shv.w = btv.w - mnv.w * scv.w;
    float4 at2 = {0.f, 0.f, 0.f, 0.f}, dt2 = {0.f, 0.f, 0.f, 0.f};
    if (q < 10) {
        at2 = *(const float4*)(ats2 + 4 * q);
        dt2 = *(const float4*)(atd2 + 4 * q);
    }

    for (int node0 = blockIdx.x * 16; node0 < n; node0 += gridDim.x * 16) {
        const int node = node0 + gi;
        if (node >= n) continue;

        const float4 adv = *(const float4*)(ad1 + node * HEADS);
        const float4 sv4 = *(const float4*)(as1 + node * HEADS);
        float4 eself;
        eself.x = __expf(leaky(sv4.x + adv.x));
        eself.y = __expf(leaky(sv4.y + adv.y));
        eself.z = __expf(leaky(sv4.z + adv.z));
        eself.w = __expf(leaky(sv4.w + adv.w));
        const float es = (myh == 0) ? eself.x : (myh == 1) ? eself.y
                       : (myh == 2) ? eself.z : eself.w;

        float2 raws = *(const float2*)(h1 + (size_t)node * HC + 4 * q);
        const float2 s0 = __half22float2(*(__half2*)&raws.x);
        const float2 s1 = __half22float2(*(__half2*)&raws.y);
        float4 acc;
        acc.x = es * s0.x; acc.y = es * s0.y;
        acc.z = es * s1.x; acc.w = es * s1.y;
        float4 dpart = {0.f, 0.f, 0.f, 0.f};

        const int start = (node == 0) ? 0 : rowptr[node - 1];
        const int end   = rowptr[node];

        for (int base = start; base < end; base += 32) {
            const int m = min(32, end - base);
            float4 ea = {0.f, 0.f, 0.f, 0.f}, eb = {0.f, 0.f, 0.f, 0.f};
            int ia = 0, ib = 0;
            if (q < m) {
                ia = csr[base + q];
                const float4 s4 = *(const float4*)(as1 + (size_t)ia * HEADS);
                ea.x = __expf(leaky(s4.x + adv.x));
                ea.y = __expf(leaky(s4.y + adv.y));
                ea.z = __expf(leaky(s4.z + adv.z));
                ea.w = __expf(leaky(s4.w + adv.w));
            }
            if (q + 16 < m) {
                ib = csr[base + q + 16];
                const float4 s4 = *(const float4*)(as1 + (size_t)ib * HEADS);
                eb.x = __expf(leaky(s4.x + adv.x));
                eb.y = __expf(leaky(s4.y + adv.y));
                eb.z = __expf(leaky(s4.z + adv.z));
                eb.w = __expf(leaky(s4.w + adv.w));
            }
            dpart.x += ea.x + eb.x; dpart.y += ea.y + eb.y;
            dpart.z += ea.z + eb.z; dpart.w += ea.w + eb.w;
            *(float4*)&sE[gi][4 * q] = ea;
            *(float4*)&sE[gi][4 * (q + 16)] = eb;
            sS[gi][q] = ia; sS[gi][q + 16] = ib;
            __threadfence_block();

            int j = 0;
            for (; j + 2 <= m; j += 2) {
                const int sa = sS[gi][j], sb = sS[gi][j + 1];
                const float fa = sE[gi][4 * j + myh];
                const float fb = sE[gi][4 * (j + 1) + myh];
                const float2 ra = *(const float2*)(h1 + (size_t)sa * HC + 4 * q);
                const float2 rb = *(const float2*)(h1 + (size_t)sb * HC + 4 * q);
                const float2 a0 = __half22float2(*(const __half2*)&ra.x);
                const float2 a1 = __half22float2(*(const __half2*)&ra.y);
                const float2 b0 = __half22float2(*(const __half2*)&rb.x);
                const float2 b1 = __half22float2(*(const __half2*)&rb.y);
                acc.x = fmaf(fa, a0.x, acc.x); acc.y = fmaf(fa, a0.y, acc.y);
                acc.z = fmaf(fa, a1.x, acc.z); acc.w = fmaf(fa, a1.y, acc.w);
                acc.x = fmaf(fb, b0.x, acc.x); acc.y = fmaf(fb, b0.y, acc.y);
                acc.z = fmaf(fb, b1.x, acc.z); acc.w = fmaf(fb, b1.y, acc.w);
            }
            if (j < m) {
                const int sa = sS[gi][j];
                const float fa = sE[gi][4 * j + myh];
                const float2 ra = *(const float2*)(h1 + (size_t)sa * HC + 4 * q);
                const float2 a0 = __half22float2(*(const __half2*)&ra.x);
                const float2 a1 = __half22float2(*(const __half2*)&ra.y);
                acc.x = fmaf(fa, a0.x, acc.x); acc.y = fmaf(fa, a0.y, acc.y);
                acc.z = fmaf(fa, a1.x, acc.z); acc.w = fmaf(fa, a1.y, acc.w);
            }
            __threadfence_block();
        }

        #pragma unroll
        for (int off = 8; off >= 1; off >>= 1) {
            dpart.x += __shfl_xor(dpart.x, off, 64);
            dpart.y += __shfl_xor(dpart.y, off, 64);
            dpart.z += __shfl_xor(dpart.z, off, 64);
            dpart.w += __shfl_xor(dpart.w, off, 64);
        }
        const float den = es + ((myh == 0) ? dpart.x : (myh == 1) ? dpart.y
                               : (myh == 2) ? dpart.z : dpart.w);
        const float rden = 1.f / den;

        float4 v;
        v.x = fmaxf(fmaf(acc.x * rden + b1v.x, scv.x, shv.x), 0.f);
        v.y = fmaxf(fmaf(acc.y * rden + b1v.y, scv.y, shv.y), 0.f);
        v.z = fmaxf(fmaf(acc.z * rden + b1v.z, scv.z, shv.z), 0.f);
        v.w = fmaxf(fmaf(acc.w * rden + b1v.w, scv.w, shv.w), 0.f);
        *(float4*)&sh[gi][4 * q] = v;
        __threadfence_block();

        float4 gacc = {0.f, 0.f, 0.f, 0.f};
        if (q < 10) {
            #pragma unroll 8
            for (int k = 0; k < HC; ++k) {
                const float hk = sh[gi][k];
                const float4 wv = *(const float4*)&sW[k * NCLASS + 4 * q];
                gacc.x = fmaf(hk, wv.x, gacc.x);
                gacc.y = fmaf(hk, wv.y, gacc.y);
                gacc.z = fmaf(hk, wv.z, gacc.z);
                gacc.w = fmaf(hk, wv.w, gacc.w);
            }
        }
        __half2 p0 = __float22half2_rn({gacc.x, gacc.y});
        __half2 p1 = __float22half2_rn({gacc.z, gacc.w});
        float2 packed; *(__half2*)&packed.x = p0; *(__half2*)&packed.y = p1;
        *(float2*)(g + (size_t)node * HC + 4 * q) = packed;

        float sv = gacc.x * at2.x + gacc.y * at2.y + gacc.z * at2.z + gacc.w * at2.w;
        float dv = gacc.x * dt2.x + gacc.y * dt2.y + gacc.z * dt2.z + gacc.w * dt2.w;
        #pragma unroll
        for (int off = 8; off >= 1; off >>= 1) {
            sv += __shfl_xor(sv, off, 64);
            dv += __shfl_xor(dv, off, 64);
        }
        if (q == 0) { as2o[node] = sv; ad2o[node] = dv; }
        __threadfence_block();
    }
}

// ---------------------------------------------------------------------------
// Kernel agg2: one 16-lane group per node; g rows padded to 64 fp16 ch.
// ---------------------------------------------------------------------------
__global__ __launch_bounds__(256) void k_agg2(
    const int* __restrict__ csr, const int* __restrict__ rowptr,
    const __half* __restrict__ g, const float* __restrict__ as2,
    const float* __restrict__ ad2, const float* __restrict__ bias2,
    float* __restrict__ out, int n)
{
    __shared__ float sE[16][34];
    __shared__ int   sS[16][33];
    const int gi = threadIdx.x >> 4;
    const int q  = threadIdx.x & 15;

    float4 b2v = {0.f, 0.f, 0.f, 0.f};
    if (q < 10) b2v = *(const float4*)(bias2 + 4 * q);

    for (int node0 = blockIdx.x * 16; node0 < n; node0 += gridDim.x * 16) {
        const int node = node0 + gi;
        if (node >= n) continue;

        const float ad2d = ad2[node];
        const float eself = __expf(leaky(as2[node] + ad2d));

        float2 raws = *(const float2*)(g + (size_t)node * HC + 4 * q);
        const float2 s0 = __half22float2(*(__half2*)&raws.x);
        const float2 s1 = __half22float2(*(__half2*)&raws.y);
        float4 acc;
        acc.x = eself * s0.x; acc.y = eself * s0.y;
        acc.z = eself * s1.x; acc.w = eself * s1.y;
        float dpart = 0.f;

        const int start = (node == 0) ? 0 : rowptr[node - 1];
        const int end   = rowptr[node];

        for (int base = start; base < end; base += 32) {
            const int m = min(32, end - base);
            float ea = 0.f, eb = 0.f;
            int ia = 0, ib = 0;
            if (q < m) {
                ia = csr[base + q];
                ea = __expf(leaky(as2[ia] + ad2d));
            }
            if (q + 16 < m) {
                ib = csr[base + q + 16];
                eb = __expf(leaky(as2[ib] + ad2d));
            }
            dpart += ea + eb;
            sE[gi][q] = ea; sE[gi][q + 16] = eb;
            sS[gi][q] = ia; sS[gi][q + 16] = ib;
            __threadfence_block();

            int j = 0;
            for (; j + 2 <= m; j += 2) {
                const int sa = sS[gi][j], sb = sS[gi][j + 1];
                const float fa = sE[gi][j], fb = sE[gi][j + 1];
                const float2 ra = *(const float2*)(g + (size_t)sa * HC + 4 * q);
                const float2 rb = *(const float2*)(g + (size_t)sb * HC + 4 * q);
                const float2 a0 = __half22float2(*(const __half2*)&ra.x);
                const float2 a1 = __half22float2(*(const __half2*)&ra.y);
                const float2 b0 = __half22float2(*(const __half2*)&rb.x);
                const float2 b1 = __half22float2(*(const __half2*)&rb.y);
                acc.x = fmaf(fa, a0.x, acc.x); acc.y = fmaf(fa, a0.y, acc.y);
                acc.z = fmaf(fa, a1.x, acc.z); acc.w = fmaf(fa, a1.y, acc.w);
                acc.x = fmaf(fb, b0.x, acc.x); acc.y = fmaf(fb, b0.y, acc.y);
                acc.z = fmaf(fb, b1.x, acc.z); acc.w = fmaf(fb, b1.y, acc.w);
            }
            if (j < m) {
                const int sa = sS[gi][j];
                const float fa = sE[gi][j];
                const float2 ra = *(const float2*)(g + (size_t)sa * HC + 4 * q);
                const float2 a0 = __half22float2(*(const __half2*)&ra.x);
                const float2 a1 = __half22float2(*(const __half2*)&ra.y);
                acc.x = fmaf(fa, a0.x, acc.x); acc.y = fmaf(fa, a0.y, acc.y);
                acc.z = fmaf(fa, a1.x, acc.z); acc.w = fmaf(fa, a1.y, acc.w);
            }
            __threadfence_block();
        }

        #pragma unroll
        for (int off = 8; off >= 1; off >>= 1)
            dpart += __shfl_xor(dpart, off, 64);
        const float rden = 1.f / (dpart + eself);

        if (q < 10) {
            float4 r;
            r.x = acc.x * rden + b2v.x;
            r.y = acc.y * rden + b2v.y;
            r.z = acc.z * rden + b2v.z;
            r.w = acc.w * rden + b2v.w;
            *(float4*)(out + (size_t)node * NCLASS + 4 * q) = r;
        }
    }
}

extern "C" void kernel_launch(void* const* d_in, const int* in_sizes, int n_in,
                              void* d_out, int out_size, void* d_ws, size_t ws_size,
                              hipStream_t stream)
{
    const float* x    = (const float*)d_in[0];
    const int*   ei   = (const int*)  d_in[1];
    const float* W1   = (const float*)d_in[2];
    const float* as1w = (const float*)d_in[3];
    const float* ad1w = (const float*)d_in[4];
    const float* b1   = (const float*)d_in[5];
    const float* gm   = (const float*)d_in[6];
    const float* bt   = (const float*)d_in[7];
    const float* mn   = (const float*)d_in[8];
    const float* vr   = (const float*)d_in[9];
    const float* W2   = (const float*)d_in[10];
    const float* as2w = (const float*)d_in[11];
    const float* ad2w = (const float*)d_in[12];
    const float* b2   = (const float*)d_in[13];

    const int n = in_sizes[0] / NFEAT;           // 100000
    const int E = in_sizes[1] / 2;               // 1600000
    const int* esrc = ei;
    const int* edst = ei + E;

    const int nbk = (n + 511) >> BK_SH;          // 196 buckets
    const int nw  = (E + CHUNK - 1) / CHUNK;     // 196 chunks

    float*  ws   = (float*)d_ws;
    __half* h1   = (__half*)ws;
    float*  a_s1 = ws   + (size_t)n * 32;
    float*  a_d1 = a_s1 + (size_t)n * 4;
    __half* gbuf = (__half*)(a_d1 + (size_t)n * 4);
    float*  a_s2 = a_d1 + (size_t)n * 4 + (size_t)n * 32;
    float*  a_d2 = a_s2 + n;
    int2*   pairs  = (int2*)(a_d2 + n);
    int*    csr    = (int*)(pairs + E);
    int*    rowptr = csr + E;
    int*    hist   = rowptr + n;
    int*    colsum = hist + (size_t)nw * nbk;
    int*    bstart = colsum + nbk;
    float*  outv = (float*)d_out;

    const int nblk = (n + 15) / 16;

    k_hist   <<<nw, 256, 0, stream>>>(edst, hist, E, nbk);
    k_colscan<<<nbk, 256, 0, stream>>>(hist, colsum, nbk, nw);
    k_bscan  <<<1, 256, 0, stream>>>(colsum, bstart, nbk, E);
    k_scatter<<<nw, 256, 0, stream>>>(esrc, edst, hist, bstart, pairs, E, nbk);
    k_build  <<<nbk, 256, 0, stream>>>(pairs, bstart, rowptr, csr, n, nbk);
    k_gemm1  <<<512, 256, 0, stream>>>(x, W1, as1w, ad1w, h1, a_s1, a_d1, n);
    k_agg1   <<<nblk, 256, 0, stream>>>(csr, rowptr, h1, a_s1, a_d1, b1, gm, bt, mn, vr,
                                        W2, as2w, ad2w, gbuf, a_s2, a_d2, n);
    k_agg2   <<<nblk, 256, 0, stream>>>(csr, rowptr, gbuf, a_s2, a_d2, b2, outv, n);
}